// Round 4
// baseline (206.334 us; speedup 1.0000x reference)
//
#include <hip/hip_runtime.h>

// Problem constants
#define NB 4      // batch
#define NI 160    // input spatial size (all 3 dims)
#define NO 43     // output spatial size: ceil(160/4)+3
#define NC 3      // channels
#define KS 7      // gaussian kernel size per axis
#define KPAD 3    // (KS-1)/2
#define MT 16     // stored taps per banded row (true max = 14)
#define CH 8      // rows per chunk (fallback)

#define ROWF (NI * NC)            // 480 floats per input row
#define PROW 132                  // padded (o3,c) row: 129 -> 132 floats
#define PROW4 (PROW / 4)          // 33 float4
#define LROW 484                  // LDS row stride in floats (484 % 32 == 4)
#define SLICE (NO * NO * NC)      // 5547

#define A1_BYTES ((size_t)NB * NI * NI * PROW * 4)       // 54,067,200
#define A2_BYTES ((size_t)NB * NI * NO * PROW * 4)       // 14,530,560
#define P2_THREADS ((size_t)NB * NI * NO * PROW4)        // 908,160
#define P3_THREADS ((size_t)NB * NO * NO * PROW4)        // 244,068

// Workspace layout (bytes):
//  0      : wa3[43*20] f32   aligned 20-float weight windows, axis i3
//  3456   : j3[43] i32       window starts (multiples of 4)
//  4096   : w1[43*16] f32    axis i2 weights
//  8192   : o1[43*16] i32    axis i2 clamped byte offsets (stride 528)
//  12288  : w0[43*16] f32    axis i1 weights
//  16384  : o0[43*16] i32    axis i1 clamped byte offsets (stride 22704)
//  32768  : A1 (54.1 MB) [b][i1][i2][132]
//  then   : A2 (14.5 MB) [b][i1][o2][132]
// Fallback path reuses 0..: wtab/wstart (old layout) + S @32768.

// ---------------------------------------------------------------------------
// Device helper: composite band weights for one axis row.
// ---------------------------------------------------------------------------
__device__ __forceinline__ void band_params(int o, int* ilo_, int* ihi_,
                                            float* sf_, float* wsum_) {
    const float inv_scale = (float)NI / (float)NO;
    const float ksc = inv_scale;
    float sf = ((float)o + 0.5f) * inv_scale - 0.5f;
    int ilo = (int)ceilf(sf - ksc);  if (ilo < 0) ilo = 0;
    int ihi = (int)floorf(sf + ksc); if (ihi > NI - 1) ihi = NI - 1;
    float wsum = 0.f;
    for (int i = ilo; i <= ihi; ++i)
        wsum += fmaxf(0.f, 1.f - fabsf(sf - (float)i) / ksc);
    *ilo_ = ilo; *ihi_ = ihi; *sf_ = sf; *wsum_ = wsum;
}

__device__ __forceinline__ float comp_weight(int j, int ilo, int ihi, float sf,
                                             float wsum, const float* gax) {
    const float ksc = (float)NI / (float)NO;
    int jlo = ilo - KPAD; if (jlo < 0) jlo = 0;
    int jhi = ihi + KPAD; if (jhi > NI - 1) jhi = NI - 1;
    if (j < jlo || j > jhi) return 0.f;
    float cw = 0.f;
    for (int tt = 0; tt < KS; ++tt) {
        int i = j + KPAD - tt;
        if (i >= ilo && i <= ihi) {
            float w = fmaxf(0.f, 1.f - fabsf(sf - (float)i) / ksc) / wsum;
            cw += gax[tt] * w;
        }
    }
    return cw;
}

// ---------------------------------------------------------------------------
// Setup (fast path): marginals + all tap tables.
// ---------------------------------------------------------------------------
__global__ void k_setup2(const float* __restrict__ kern,
                         float* __restrict__ wa3, int* __restrict__ j3,
                         float* __restrict__ w1, int* __restrict__ o1,
                         float* __restrict__ w0, int* __restrict__ o0) {
    __shared__ float g[3 * KS];
    int t = threadIdx.x;
    if (t < 3 * KS) {
        int ax = t / KS, idx = t % KS;
        float s = 0.f;
        for (int a = 0; a < KS; ++a)
            for (int b = 0; b < KS; ++b) {
                int i0 = (ax == 0) ? idx : a;
                int i1 = (ax == 1) ? idx : ((ax == 0) ? a : b);
                int i2 = (ax == 2) ? idx : b;
                s += kern[(i0 * KS + i1) * KS + i2];
            }
        g[t] = s;
    }
    __syncthreads();

    if (t < NO) {
        int ilo, ihi; float sf, wsum;
        band_params(t, &ilo, &ihi, &sf, &wsum);
        int jlo = ilo - KPAD; if (jlo < 0) jlo = 0;

        // axis i3: aligned 20-float window
        int j0 = jlo & ~3;
        j3[t] = j0;
        for (int m = 0; m < 20; ++m)
            wa3[t * 20 + m] = comp_weight(j0 + m, ilo, ihi, sf, wsum, g + 2 * KS);

        // axis i2: 16-tap band, byte offsets stride PROW*4 = 528
        for (int k = 0; k < MT; ++k) {
            int j = jlo + k;
            w1[t * MT + k] = comp_weight(j, ilo, ihi, sf, wsum, g + KS);
            int jc = (j < NI) ? j : (NI - 1);
            o1[t * MT + k] = jc * (PROW * 4);
        }
        // axis i1: stride NO*PROW*4 = 22704
        for (int k = 0; k < MT; ++k) {
            int j = jlo + k;
            w0[t * MT + k] = comp_weight(j, ilo, ihi, sf, wsum, g);
            int jc = (j < NI) ? j : (NI - 1);
            o0[t * MT + k] = jc * (NO * PROW * 4);
        }
    }
}

// ---------------------------------------------------------------------------
// P1: contract i3 -> o3.  A1[b][i1][i2][o3*3+c] (rows padded to 132).
// Block stages 8 contiguous input rows; vector LDS (b128) everywhere.
// ---------------------------------------------------------------------------
__global__ __launch_bounds__(256, 4) void k_p1(
        const float* __restrict__ img, const float* __restrict__ wa3,
        const int* __restrict__ j3, float* __restrict__ A1) {
    __shared__ __align__(16) float rows[8 * LROW + 64];   // 3936 f
    __shared__ __align__(16) float swa[NO * 20];          // 860 f
    __shared__ int sj0[NO];
    int t = threadIdx.x;
    int blk = blockIdx.x;                                  // (b*160+i1)*20 + chunk

    // stage 8 rows (15.36 KB, coalesced float4 -> aligned b128 writes)
    const float4* src = (const float4*)(img + (size_t)blk * (8 * ROWF));
    for (int gidx = t; gidx < 8 * ROWF / 4; gidx += 256) {
        int row = gidx / (ROWF / 4), m = gidx % (ROWF / 4);
        *(float4*)(rows + row * LROW + 4 * m) = src[gidx];
    }
    // zero row pads [480,484) and tail slack
    if (t < 32) rows[(t >> 2) * LROW + ROWF + (t & 3)] = 0.f;
    if (t < 64) rows[8 * LROW + t] = 0.f;
    // weight tables -> LDS
    for (int k = t; k < NO * 20 / 4; k += 256)
        ((float4*)swa)[k] = ((const float4*)wa3)[k];
    if (t < NO) sj0[t] = j3[t];
    __syncthreads();

    float* dst = A1 + (size_t)blk * (8 * PROW);
    for (int task = t; task < NO * 8; task += 256) {
        int o3 = task >> 3, row = task & 7;
        int j0 = sj0[o3];
        const float4* dp = (const float4*)(rows + row * LROW + 3 * j0);
        const float4* wp = (const float4*)(swa + o3 * 20);
        float d[60], wv[20];
        #pragma unroll
        for (int m = 0; m < 15; ++m) {
            float4 v = dp[m];
            d[4 * m + 0] = v.x; d[4 * m + 1] = v.y;
            d[4 * m + 2] = v.z; d[4 * m + 3] = v.w;
        }
        #pragma unroll
        for (int m = 0; m < 5; ++m) {
            float4 v = wp[m];
            wv[4 * m + 0] = v.x; wv[4 * m + 1] = v.y;
            wv[4 * m + 2] = v.z; wv[4 * m + 3] = v.w;
        }
        float a0 = 0.f, a1 = 0.f, a2 = 0.f;
        #pragma unroll
        for (int jj = 0; jj < 20; ++jj) {
            float w = wv[jj];
            a0 += w * d[3 * jj + 0];
            a1 += w * d[3 * jj + 1];
            a2 += w * d[3 * jj + 2];
        }
        float* op = dst + row * PROW + o3 * 3;
        op[0] = a0; op[1] = a1; op[2] = a2;
    }
    // zero pad cols 129..131 of the 8 rows
    if (t < 8) {
        float* op = dst + t * PROW + NO * NC;
        op[0] = 0.f; op[1] = 0.f; op[2] = 0.f;
    }
}

// Bijective XCD-chunked block swizzle (m204 form).
__device__ __forceinline__ int xcd_swz(int wg, int nwg) {
    int q = nwg >> 3, r = nwg & 7;
    int x = wg & 7, i = wg >> 3;
    return (x < r ? x * (q + 1) : r * (q + 1) + (x - r) * q) + i;
}

// ---------------------------------------------------------------------------
// P2: contract i2 -> o2.  A2[b][i1][o2][132]. Thread per float4.
// ---------------------------------------------------------------------------
__global__ __launch_bounds__(256) void k_p2(
        const float* __restrict__ A1, const float* __restrict__ w1,
        const int* __restrict__ o1, float* __restrict__ A2) {
    int blk = xcd_swz(blockIdx.x, gridDim.x);
    size_t idx = (size_t)blk * 256 + threadIdx.x;
    if (idx >= P2_THREADS) return;
    int ii = (int)idx;
    int col4 = ii % PROW4;
    int o2   = (ii / PROW4) % NO;
    int slab = ii / (PROW4 * NO);           // b*160 + i1
    const char* base = (const char*)A1 + ((size_t)slab * NI * PROW + col4 * 4) * 4;
    const float4* wv = (const float4*)(w1 + o2 * MT);
    const int4*   ov = (const int4*)(o1 + o2 * MT);
    float4 w0 = wv[0], w1v = wv[1], w2 = wv[2], w3 = wv[3];
    int4   j0 = ov[0], j1 = ov[1], j2 = ov[2], j3 = ov[3];
    float4 a = {0.f, 0.f, 0.f, 0.f};
#define TAP4(J, W) { float4 v = *(const float4*)(base + (unsigned)(J)); \
                     a.x += (W) * v.x; a.y += (W) * v.y; a.z += (W) * v.z; a.w += (W) * v.w; }
    TAP4(j0.x, w0.x) TAP4(j0.y, w0.y) TAP4(j0.z, w0.z) TAP4(j0.w, w0.w)
    TAP4(j1.x, w1v.x) TAP4(j1.y, w1v.y) TAP4(j1.z, w1v.z) TAP4(j1.w, w1v.w)
    TAP4(j2.x, w2.x) TAP4(j2.y, w2.y) TAP4(j2.z, w2.z) TAP4(j2.w, w2.w)
    TAP4(j3.x, w3.x) TAP4(j3.y, w3.y) TAP4(j3.z, w3.z) TAP4(j3.w, w3.w)
#undef TAP4
    ((float4*)A2)[idx] = a;
}

// ---------------------------------------------------------------------------
// P3: contract i1 -> o1.  out[b][o1][o2][o3][c] (unpadded 129 cols).
// ---------------------------------------------------------------------------
__global__ __launch_bounds__(256) void k_p3(
        const float* __restrict__ A2, const float* __restrict__ w0t,
        const int* __restrict__ o0t, float* __restrict__ out) {
    int blk = xcd_swz(blockIdx.x, gridDim.x);
    size_t idx = (size_t)blk * 256 + threadIdx.x;
    if (idx >= P3_THREADS) return;
    int ii = (int)idx;
    int col4 = ii % PROW4;
    int o2   = (ii / PROW4) % NO;
    int o1   = (ii / (PROW4 * NO)) % NO;
    int b    = ii / (PROW4 * NO * NO);
    const char* base = (const char*)A2 +
        (((size_t)b * NI * NO + o2) * PROW + col4 * 4) * 4;
    const float4* wv = (const float4*)(w0t + o1 * MT);
    const int4*   ov = (const int4*)(o0t + o1 * MT);
    float4 w0 = wv[0], w1v = wv[1], w2 = wv[2], w3 = wv[3];
    int4   j0 = ov[0], j1 = ov[1], j2 = ov[2], j3 = ov[3];
    float4 a = {0.f, 0.f, 0.f, 0.f};
#define TAP4(J, W) { float4 v = *(const float4*)(base + (unsigned)(J)); \
                     a.x += (W) * v.x; a.y += (W) * v.y; a.z += (W) * v.z; a.w += (W) * v.w; }
    TAP4(j0.x, w0.x) TAP4(j0.y, w0.y) TAP4(j0.z, w0.z) TAP4(j0.w, w0.w)
    TAP4(j1.x, w1v.x) TAP4(j1.y, w1v.y) TAP4(j1.z, w1v.z) TAP4(j1.w, w1v.w)
    TAP4(j2.x, w2.x) TAP4(j2.y, w2.y) TAP4(j2.z, w2.z) TAP4(j2.w, w2.w)
    TAP4(j3.x, w3.x) TAP4(j3.y, w3.y) TAP4(j3.z, w3.z) TAP4(j3.w, w3.w)
#undef TAP4
    int tile = (b * NO + o1) * NO + o2;
    float* ob = out + (size_t)tile * (NO * NC) + col4 * 4;
    int col = col4 * 4;
    float av[4] = {a.x, a.y, a.z, a.w};
    #pragma unroll
    for (int e = 0; e < 4; ++e)
        if (col + e < NO * NC) ob[e] = av[e];
}

// ---------------------------------------------------------------------------
// FALLBACK (round-1, known-correct): fused pass A + pass B, small ws.
// ---------------------------------------------------------------------------
__global__ void k_setup(const float* __restrict__ kern,
                        float* __restrict__ wtab, int* __restrict__ wstart) {
    __shared__ float g[3 * KS];
    int t = threadIdx.x;
    if (t < 3 * KS) {
        int ax = t / KS, idx = t % KS;
        float s = 0.f;
        for (int a = 0; a < KS; ++a)
            for (int b = 0; b < KS; ++b) {
                int i0 = (ax == 0) ? idx : a;
                int i1 = (ax == 1) ? idx : ((ax == 0) ? a : b);
                int i2 = (ax == 2) ? idx : b;
                s += kern[(i0 * KS + i1) * KS + i2];
            }
        g[t] = s;
    }
    __syncthreads();
    for (int row = t; row < 3 * NO; row += blockDim.x) {
        int ax = row / NO, o = row % NO;
        int ilo, ihi; float sf, wsum;
        band_params(o, &ilo, &ihi, &sf, &wsum);
        int jlo = ilo - KPAD; if (jlo < 0) jlo = 0;
        wstart[row] = jlo;
        for (int k = 0; k < MT; ++k)
            wtab[row * MT + k] = comp_weight(jlo + k, ilo, ihi, sf, wsum, g + ax * KS);
    }
}

__global__ __launch_bounds__(256) void k_passA(
        const float* __restrict__ img, const float* __restrict__ wtab,
        const int* __restrict__ wstart, float* __restrict__ S) {
    __shared__ float rows[CH * NI * NC];
    __shared__ float T[CH * NO * NC];
    __shared__ float acc[NO * NO * NC];
    __shared__ float w2[NO * MT], w3[NO * MT];
    __shared__ int   s2[NO], s3[NO];
    int t = threadIdx.x;
    int blk = blockIdx.x;
    const float* src = img + (size_t)blk * (NI * NI * NC);
    for (int k = t; k < NO * MT; k += 256) {
        w2[k] = wtab[NO * MT + k];
        w3[k] = wtab[2 * NO * MT + k];
    }
    for (int k = t; k < NO; k += 256) { s2[k] = wstart[NO + k]; s3[k] = wstart[2 * NO + k]; }
    for (int k = t; k < NO * NO * NC; k += 256) acc[k] = 0.f;
    __syncthreads();
    for (int chunk = 0; chunk < NI / CH; ++chunk) {
        const float4* csrc = (const float4*)(src + (size_t)chunk * CH * NI * NC);
        for (int k = t; k < CH * NI * NC / 4; k += 256)
            ((float4*)rows)[k] = csrc[k];
        __syncthreads();
        for (int task = t; task < CH * NO; task += 256) {
            int ch = task / NO, o3 = task % NO;
            int st = s3[o3];
            const float* rp = rows + ch * NI * NC;
            float a0 = 0.f, a1 = 0.f, a2 = 0.f;
            #pragma unroll
            for (int k = 0; k < MT; ++k) {
                int j = st + k; j = (j < NI) ? j : (NI - 1);
                float w = w3[o3 * MT + k];
                a0 += w * rp[j * 3 + 0];
                a1 += w * rp[j * 3 + 1];
                a2 += w * rp[j * 3 + 2];
            }
            T[task * NC + 0] = a0;
            T[task * NC + 1] = a1;
            T[task * NC + 2] = a2;
        }
        __syncthreads();
        int i2base = chunk * CH;
        for (int task = t; task < NO * NO; task += 256) {
            int o2 = task / NO, o3 = task % NO;
            int st = s2[o2];
            int k0 = i2base - st;        k0 = (k0 > 0) ? k0 : 0;
            int k1 = i2base + CH - st;   k1 = (k1 < MT) ? k1 : MT;
            if (k1 > k0) {
                float a0 = 0.f, a1 = 0.f, a2 = 0.f;
                for (int k = k0; k < k1; ++k) {
                    float w = w2[o2 * MT + k];
                    int ch = st + k - i2base;
                    a0 += w * T[(ch * NO + o3) * NC + 0];
                    a1 += w * T[(ch * NO + o3) * NC + 1];
                    a2 += w * T[(ch * NO + o3) * NC + 2];
                }
                acc[task * NC + 0] += a0;
                acc[task * NC + 1] += a1;
                acc[task * NC + 2] += a2;
            }
        }
        __syncthreads();
    }
    float* Sp = S + (size_t)blk * (NO * NO * NC);
    for (int k = t; k < NO * NO * NC; k += 256) Sp[k] = acc[k];
}

__global__ __launch_bounds__(256) void k_passB(
        const float* __restrict__ S, const float* __restrict__ wtab,
        const int* __restrict__ wstart, float* __restrict__ out) {
    int blk = blockIdx.x;
    int b = blk / NO, o1 = blk % NO;
    __shared__ float w1s[MT];
    __shared__ int s1v;
    if (threadIdx.x < MT) w1s[threadIdx.x] = wtab[o1 * MT + threadIdx.x];
    if (threadIdx.x == 0) s1v = wstart[o1];
    __syncthreads();
    const float* Sb = S + (size_t)b * NI * (NO * NO * NC);
    float* ob = out + (size_t)blk * (NO * NO * NC);
    int st = s1v;
    for (int e = threadIdx.x; e < NO * NO * NC; e += 256) {
        float a = 0.f;
        #pragma unroll
        for (int k = 0; k < MT; ++k) {
            int i1 = st + k; i1 = (i1 < NI) ? i1 : (NI - 1);
            a += w1s[k] * Sb[(size_t)i1 * (NO * NO * NC) + e];
        }
        ob[e] = a;
    }
}

// ---------------------------------------------------------------------------
extern "C" void kernel_launch(void* const* d_in, const int* in_sizes, int n_in,
                              void* d_out, int out_size, void* d_ws, size_t ws_size,
                              hipStream_t stream) {
    (void)in_sizes; (void)n_in; (void)out_size;
    const float* img  = (const float*)d_in[0];
    const float* kern = (const float*)d_in[1];
    float* out = (float*)d_out;
    char* ws = (char*)d_ws;

    const size_t TAB = 32768;
    if (ws_size >= TAB + A1_BYTES + A2_BYTES) {
        float* wa3 = (float*)ws;
        int*   j3  = (int*)(ws + 3456);
        float* w1  = (float*)(ws + 4096);
        int*   o1  = (int*)(ws + 8192);
        float* w0  = (float*)(ws + 12288);
        int*   o0  = (int*)(ws + 16384);
        float* A1  = (float*)(ws + TAB);
        float* A2  = (float*)(ws + TAB + A1_BYTES);

        k_setup2<<<1, 64, 0, stream>>>(kern, wa3, j3, w1, o1, w0, o0);
        k_p1<<<NB * NI * (NI / 8), 256, 0, stream>>>(img, wa3, j3, A1);
        int p2b = (int)((P2_THREADS + 255) / 256);
        k_p2<<<p2b, 256, 0, stream>>>(A1, w1, o1, A2);
        int p3b = (int)((P3_THREADS + 255) / 256);
        k_p3<<<p3b, 256, 0, stream>>>(A2, w0, o0, out);
    } else {
        float* wtab   = (float*)ws;
        int*   wstart = (int*)(ws + 8256);
        float* S      = (float*)(ws + TAB);
        k_setup<<<1, 256, 0, stream>>>(kern, wtab, wstart);
        k_passA<<<NB * NI, 256, 0, stream>>>(img, wtab, wstart, S);
        k_passB<<<NB * NO, 256, 0, stream>>>(S, wtab, wstart, out);
    }
}

// Round 6
// 81.266 us; speedup vs baseline: 2.5390x; 2.5390x over previous
//
#include <hip/hip_runtime.h>

// Problem constants
#define NB 4      // batch
#define NI 160    // input spatial size (all 3 dims)
#define NO 43     // output spatial size: ceil(160/4)+3
#define NC 3      // channels
#define KS 7      // gaussian kernel size per axis
#define KPAD 3    // (KS-1)/2
#define MT 16     // stored taps per banded row (true max = 14)
#define CH 8      // rows per chunk (fallback)

#define ROWF (NI * NC)            // 480 floats per input row
#define PROW 132                  // padded (o3,c) row: 129 -> 132 floats
#define PROW4 (PROW / 4)          // 33 float4
#define LROW 484                  // LDS row stride in floats (484 % 32 == 4)
#define SLICE (NO * NO * NC)      // 5547

#define A1_BYTES ((size_t)NB * NI * NI * PROW * 4)       // 54,067,200
#define A2_BYTES ((size_t)NB * NI * NO * PROW * 4)       // 14,530,560
#define P2_THREADS ((size_t)NB * NI * NO * PROW4)        // 908,160
#define P3_THREADS ((size_t)NB * NO * NO * PROW4)        // 244,068

#define INV_KSC (43.0f / 160.0f)

// Workspace layout (bytes):
//  0      : wa3[43*20] f32   aligned 20-float weight windows, axis i3
//  3456   : j3[43] i32       window starts (multiples of 4)
//  4096   : w1[43*16] f32    axis i2 weights
//  8192   : o1[43*16] i32    axis i2 clamped byte offsets (stride 528)
//  12288  : w0[43*16] f32    axis i1 weights
//  16384  : o0[43*16] i32    axis i1 clamped byte offsets (stride 22704)
//  32768  : A1 (54.1 MB) [b][i1][i2][132]
//  then   : A2 (14.5 MB) [b][i1][o2][132]
// Fallback path reuses 0..: wtab/wstart (old layout) + S @32768.

// ---------------------------------------------------------------------------
// Composite weight, branch-free inner loop, no divides.
// CRITICAL: taps at j >= NI must be exactly 0 (DeepReg zero-pads the blur;
// the resize band never reaches j >= NI itself). r5 bug: missing this clause
// let clamped offsets (j->NI-1) receive nonzero weight at the top edge.
// ---------------------------------------------------------------------------
__device__ __forceinline__ float cw_fast(int j, float sf, int ilo, int ihi,
                                         float invw, const float* gax) {
    if (j >= NI) return 0.f;
    float cw = 0.f;
    #pragma unroll
    for (int tt = 0; tt < KS; ++tt) {
        int i = j + KPAD - tt;
        bool in = (i >= ilo) && (i <= ihi);
        float w = fmaxf(0.f, 1.f - fabsf(sf - (float)i) * INV_KSC);
        cw += in ? gax[tt] * w : 0.f;
    }
    return cw * invw;
}

// ---------------------------------------------------------------------------
// Setup (fast path): 3 blocks x 1024 threads, one (row,tap) task per thread.
// ---------------------------------------------------------------------------
__global__ __launch_bounds__(1024) void k_setup3(
        const float* __restrict__ kern,
        float* __restrict__ wa3, int* __restrict__ j3,
        float* __restrict__ w1t, int* __restrict__ o1t,
        float* __restrict__ w0t, int* __restrict__ o0t) {
    __shared__ float g[3 * KS];
    __shared__ float ssf[NO], sinvw[NO];
    __shared__ int   silo[NO], sihi[NO], sjlo[NO];
    int t = threadIdx.x;

    if (t < 3 * KS) {                       // per-axis marginals of the 7^3 kernel
        int ax = t / KS, idx = t % KS;
        float s = 0.f;
        for (int a = 0; a < KS; ++a)
            for (int b = 0; b < KS; ++b) {
                int i0 = (ax == 0) ? idx : a;
                int i1 = (ax == 1) ? idx : ((ax == 0) ? a : b);
                int i2 = (ax == 2) ? idx : b;
                s += kern[(i0 * KS + i1) * KS + i2];
            }
        g[t] = s;
    }
    if (t >= 64 && t < 64 + NO) {           // per-output-row band parameters
        int o = t - 64;
        const float inv_scale = 160.f / 43.f;
        float sf = ((float)o + 0.5f) * inv_scale - 0.5f;   // half-pixel centers
        int ilo = (int)ceilf(sf - inv_scale);  if (ilo < 0) ilo = 0;
        int ihi = (int)floorf(sf + inv_scale); if (ihi > NI - 1) ihi = NI - 1;
        float wsum = 0.f;
        for (int i = ilo; i <= ihi; ++i)
            wsum += fmaxf(0.f, 1.f - fabsf(sf - (float)i) * INV_KSC);
        ssf[o] = sf; silo[o] = ilo; sihi[o] = ihi; sinvw[o] = 1.f / wsum;
        int jlo = ilo - KPAD; if (jlo < 0) jlo = 0;
        sjlo[o] = jlo;
        if (blockIdx.x == 0) j3[o] = jlo & ~3;
    }
    __syncthreads();

    int task = blockIdx.x * 1024 + t;
    const int N3 = NO * 20;                 // 860 tasks: axis i3 aligned windows
    const int N2 = NO * MT;                 // 688 tasks per remaining axis
    if (task < N3) {
        int row = task / 20, m = task % 20;
        int j = (sjlo[row] & ~3) + m;
        wa3[task] = cw_fast(j, ssf[row], silo[row], sihi[row], sinvw[row], g + 2 * KS);
    } else if (task < N3 + N2) {
        int k2 = task - N3;
        int row = k2 / MT, k = k2 % MT;
        int j = sjlo[row] + k;
        w1t[k2] = cw_fast(j, ssf[row], silo[row], sihi[row], sinvw[row], g + KS);
        int jc = (j < NI) ? j : (NI - 1);   // pad taps have w=0
        o1t[k2] = jc * (PROW * 4);
    } else if (task < N3 + 2 * N2) {
        int k2 = task - N3 - N2;
        int row = k2 / MT, k = k2 % MT;
        int j = sjlo[row] + k;
        w0t[k2] = cw_fast(j, ssf[row], silo[row], sihi[row], sinvw[row], g);
        int jc = (j < NI) ? j : (NI - 1);
        o0t[k2] = jc * (NO * PROW * 4);
    }
}

// ---------------------------------------------------------------------------
// P1: contract i3 -> o3.  A1[b][i1][i2][o3*3+c] (rows padded to 132).
// Block stages 8 contiguous input rows; vector LDS (b128) everywhere.
// ---------------------------------------------------------------------------
__global__ __launch_bounds__(256, 4) void k_p1(
        const float* __restrict__ img, const float* __restrict__ wa3,
        const int* __restrict__ j3, float* __restrict__ A1) {
    __shared__ __align__(16) float rows[8 * LROW + 64];   // 3936 f
    __shared__ __align__(16) float swa[NO * 20];          // 860 f
    __shared__ int sj0[NO];
    int t = threadIdx.x;
    int blk = blockIdx.x;                                  // (b*160+i1)*20 + chunk

    // stage 8 rows (15.36 KB, coalesced float4 -> aligned b128 writes)
    const float4* src = (const float4*)(img + (size_t)blk * (8 * ROWF));
    for (int gidx = t; gidx < 8 * ROWF / 4; gidx += 256) {
        int row = gidx / (ROWF / 4), m = gidx % (ROWF / 4);
        *(float4*)(rows + row * LROW + 4 * m) = src[gidx];
    }
    // zero row pads [480,484) and tail slack
    if (t < 32) rows[(t >> 2) * LROW + ROWF + (t & 3)] = 0.f;
    if (t < 64) rows[8 * LROW + t] = 0.f;
    // weight tables -> LDS
    for (int k = t; k < NO * 20 / 4; k += 256)
        ((float4*)swa)[k] = ((const float4*)wa3)[k];
    if (t < NO) sj0[t] = j3[t];
    __syncthreads();

    float* dst = A1 + (size_t)blk * (8 * PROW);
    for (int task = t; task < NO * 8; task += 256) {
        int o3 = task >> 3, row = task & 7;
        int j0 = sj0[o3];
        const float4* dp = (const float4*)(rows + row * LROW + 3 * j0);
        const float4* wp = (const float4*)(swa + o3 * 20);
        float d[60], wv[20];
        #pragma unroll
        for (int m = 0; m < 15; ++m) {
            float4 v = dp[m];
            d[4 * m + 0] = v.x; d[4 * m + 1] = v.y;
            d[4 * m + 2] = v.z; d[4 * m + 3] = v.w;
        }
        #pragma unroll
        for (int m = 0; m < 5; ++m) {
            float4 v = wp[m];
            wv[4 * m + 0] = v.x; wv[4 * m + 1] = v.y;
            wv[4 * m + 2] = v.z; wv[4 * m + 3] = v.w;
        }
        float a0 = 0.f, a1 = 0.f, a2 = 0.f;
        #pragma unroll
        for (int jj = 0; jj < 20; ++jj) {
            float w = wv[jj];
            a0 += w * d[3 * jj + 0];
            a1 += w * d[3 * jj + 1];
            a2 += w * d[3 * jj + 2];
        }
        float* op = dst + row * PROW + o3 * 3;
        op[0] = a0; op[1] = a1; op[2] = a2;
    }
    // zero pad cols 129..131 of the 8 rows
    if (t < 8) {
        float* op = dst + t * PROW + NO * NC;
        op[0] = 0.f; op[1] = 0.f; op[2] = 0.f;
    }
}

// Bijective XCD-chunked block swizzle (m204 form).
__device__ __forceinline__ int xcd_swz(int wg, int nwg) {
    int q = nwg >> 3, r = nwg & 7;
    int x = wg & 7, i = wg >> 3;
    return (x < r ? x * (q + 1) : r * (q + 1) + (x - r) * q) + i;
}

// ---------------------------------------------------------------------------
// P2: contract i2 -> o2.  A2[b][i1][o2][132]. Thread per float4.
// ---------------------------------------------------------------------------
__global__ __launch_bounds__(256) void k_p2(
        const float* __restrict__ A1, const float* __restrict__ w1,
        const int* __restrict__ o1, float* __restrict__ A2) {
    int blk = xcd_swz(blockIdx.x, gridDim.x);
    size_t idx = (size_t)blk * 256 + threadIdx.x;
    if (idx >= P2_THREADS) return;
    int ii = (int)idx;
    int col4 = ii % PROW4;
    int o2   = (ii / PROW4) % NO;
    int slab = ii / (PROW4 * NO);           // b*160 + i1
    const char* base = (const char*)A1 + ((size_t)slab * NI * PROW + col4 * 4) * 4;
    const float4* wv = (const float4*)(w1 + o2 * MT);
    const int4*   ov = (const int4*)(o1 + o2 * MT);
    float4 w0 = wv[0], w1v = wv[1], w2 = wv[2], w3 = wv[3];
    int4   j0 = ov[0], j1 = ov[1], j2 = ov[2], j3 = ov[3];
    float4 a = {0.f, 0.f, 0.f, 0.f};
#define TAP4(J, W) { float4 v = *(const float4*)(base + (unsigned)(J)); \
                     a.x += (W) * v.x; a.y += (W) * v.y; a.z += (W) * v.z; a.w += (W) * v.w; }
    TAP4(j0.x, w0.x) TAP4(j0.y, w0.y) TAP4(j0.z, w0.z) TAP4(j0.w, w0.w)
    TAP4(j1.x, w1v.x) TAP4(j1.y, w1v.y) TAP4(j1.z, w1v.z) TAP4(j1.w, w1v.w)
    TAP4(j2.x, w2.x) TAP4(j2.y, w2.y) TAP4(j2.z, w2.z) TAP4(j2.w, w2.w)
    TAP4(j3.x, w3.x) TAP4(j3.y, w3.y) TAP4(j3.z, w3.z) TAP4(j3.w, w3.w)
#undef TAP4
    ((float4*)A2)[idx] = a;
}

// ---------------------------------------------------------------------------
// P3: contract i1 -> o1.  out[b][o1][o2][o3][c] (unpadded 129 cols).
// ---------------------------------------------------------------------------
__global__ __launch_bounds__(256) void k_p3(
        const float* __restrict__ A2, const float* __restrict__ w0t,
        const int* __restrict__ o0t, float* __restrict__ out) {
    int blk = xcd_swz(blockIdx.x, gridDim.x);
    size_t idx = (size_t)blk * 256 + threadIdx.x;
    if (idx >= P3_THREADS) return;
    int ii = (int)idx;
    int col4 = ii % PROW4;
    int o2   = (ii / PROW4) % NO;
    int o1   = (ii / (PROW4 * NO)) % NO;
    int b    = ii / (PROW4 * NO * NO);
    const char* base = (const char*)A2 +
        (((size_t)b * NI * NO + o2) * PROW + col4 * 4) * 4;
    const float4* wv = (const float4*)(w0t + o1 * MT);
    const int4*   ov = (const int4*)(o0t + o1 * MT);
    float4 w0 = wv[0], w1v = wv[1], w2 = wv[2], w3 = wv[3];
    int4   j0 = ov[0], j1 = ov[1], j2 = ov[2], j3 = ov[3];
    float4 a = {0.f, 0.f, 0.f, 0.f};
#define TAP4(J, W) { float4 v = *(const float4*)(base + (unsigned)(J)); \
                     a.x += (W) * v.x; a.y += (W) * v.y; a.z += (W) * v.z; a.w += (W) * v.w; }
    TAP4(j0.x, w0.x) TAP4(j0.y, w0.y) TAP4(j0.z, w0.z) TAP4(j0.w, w0.w)
    TAP4(j1.x, w1v.x) TAP4(j1.y, w1v.y) TAP4(j1.z, w1v.z) TAP4(j1.w, w1v.w)
    TAP4(j2.x, w2.x) TAP4(j2.y, w2.y) TAP4(j2.z, w2.z) TAP4(j2.w, w2.w)
    TAP4(j3.x, w3.x) TAP4(j3.y, w3.y) TAP4(j3.z, w3.z) TAP4(j3.w, w3.w)
#undef TAP4
    int tile = (b * NO + o1) * NO + o2;
    float* ob = out + (size_t)tile * (NO * NC) + col4 * 4;
    int col = col4 * 4;
    float av[4] = {a.x, a.y, a.z, a.w};
    #pragma unroll
    for (int e = 0; e < 4; ++e)
        if (col + e < NO * NC) ob[e] = av[e];
}

// ---------------------------------------------------------------------------
// FALLBACK (round-1, known-correct): fused pass A + pass B, small ws.
// ---------------------------------------------------------------------------
__device__ __forceinline__ void band_params(int o, int* ilo_, int* ihi_,
                                            float* sf_, float* wsum_) {
    const float inv_scale = (float)NI / (float)NO;
    const float ksc = inv_scale;
    float sf = ((float)o + 0.5f) * inv_scale - 0.5f;
    int ilo = (int)ceilf(sf - ksc);  if (ilo < 0) ilo = 0;
    int ihi = (int)floorf(sf + ksc); if (ihi > NI - 1) ihi = NI - 1;
    float wsum = 0.f;
    for (int i = ilo; i <= ihi; ++i)
        wsum += fmaxf(0.f, 1.f - fabsf(sf - (float)i) / ksc);
    *ilo_ = ilo; *ihi_ = ihi; *sf_ = sf; *wsum_ = wsum;
}

__global__ void k_setup(const float* __restrict__ kern,
                        float* __restrict__ wtab, int* __restrict__ wstart) {
    __shared__ float g[3 * KS];
    int t = threadIdx.x;
    if (t < 3 * KS) {
        int ax = t / KS, idx = t % KS;
        float s = 0.f;
        for (int a = 0; a < KS; ++a)
            for (int b = 0; b < KS; ++b) {
                int i0 = (ax == 0) ? idx : a;
                int i1 = (ax == 1) ? idx : ((ax == 0) ? a : b);
                int i2 = (ax == 2) ? idx : b;
                s += kern[(i0 * KS + i1) * KS + i2];
            }
        g[t] = s;
    }
    __syncthreads();
    for (int row = t; row < 3 * NO; row += blockDim.x) {
        int ax = row / NO, o = row % NO;
        int ilo, ihi; float sf, wsum;
        band_params(o, &ilo, &ihi, &sf, &wsum);
        int jlo = ilo - KPAD; if (jlo < 0) jlo = 0;
        wstart[row] = jlo;
        float invw = 1.f / wsum;
        for (int k = 0; k < MT; ++k)
            wtab[row * MT + k] = cw_fast(jlo + k, sf, ilo, ihi, invw, g + ax * KS);
    }
}

__global__ __launch_bounds__(256) void k_passA(
        const float* __restrict__ img, const float* __restrict__ wtab,
        const int* __restrict__ wstart, float* __restrict__ S) {
    __shared__ float rows[CH * NI * NC];
    __shared__ float T[CH * NO * NC];
    __shared__ float acc[NO * NO * NC];
    __shared__ float w2[NO * MT], w3[NO * MT];
    __shared__ int   s2[NO], s3[NO];
    int t = threadIdx.x;
    int blk = blockIdx.x;
    const float* src = img + (size_t)blk * (NI * NI * NC);
    for (int k = t; k < NO * MT; k += 256) {
        w2[k] = wtab[NO * MT + k];
        w3[k] = wtab[2 * NO * MT + k];
    }
    for (int k = t; k < NO; k += 256) { s2[k] = wstart[NO + k]; s3[k] = wstart[2 * NO + k]; }
    for (int k = t; k < NO * NO * NC; k += 256) acc[k] = 0.f;
    __syncthreads();
    for (int chunk = 0; chunk < NI / CH; ++chunk) {
        const float4* csrc = (const float4*)(src + (size_t)chunk * CH * NI * NC);
        for (int k = t; k < CH * NI * NC / 4; k += 256)
            ((float4*)rows)[k] = csrc[k];
        __syncthreads();
        for (int task = t; task < CH * NO; task += 256) {
            int ch = task / NO, o3 = task % NO;
            int st = s3[o3];
            const float* rp = rows + ch * NI * NC;
            float a0 = 0.f, a1 = 0.f, a2 = 0.f;
            #pragma unroll
            for (int k = 0; k < MT; ++k) {
                int j = st + k; j = (j < NI) ? j : (NI - 1);
                float w = w3[o3 * MT + k];
                a0 += w * rp[j * 3 + 0];
                a1 += w * rp[j * 3 + 1];
                a2 += w * rp[j * 3 + 2];
            }
            T[task * NC + 0] = a0;
            T[task * NC + 1] = a1;
            T[task * NC + 2] = a2;
        }
        __syncthreads();
        int i2base = chunk * CH;
        for (int task = t; task < NO * NO; task += 256) {
            int o2 = task / NO, o3 = task % NO;
            int st = s2[o2];
            int k0 = i2base - st;        k0 = (k0 > 0) ? k0 : 0;
            int k1 = i2base + CH - st;   k1 = (k1 < MT) ? k1 : MT;
            if (k1 > k0) {
                float a0 = 0.f, a1 = 0.f, a2 = 0.f;
                for (int k = k0; k < k1; ++k) {
                    float w = w2[o2 * MT + k];
                    int ch = st + k - i2base;
                    a0 += w * T[(ch * NO + o3) * NC + 0];
                    a1 += w * T[(ch * NO + o3) * NC + 1];
                    a2 += w * T[(ch * NO + o3) * NC + 2];
                }
                acc[task * NC + 0] += a0;
                acc[task * NC + 1] += a1;
                acc[task * NC + 2] += a2;
            }
        }
        __syncthreads();
    }
    float* Sp = S + (size_t)blk * (NO * NO * NC);
    for (int k = t; k < NO * NO * NC; k += 256) Sp[k] = acc[k];
}

__global__ __launch_bounds__(256) void k_passB(
        const float* __restrict__ S, const float* __restrict__ wtab,
        const int* __restrict__ wstart, float* __restrict__ out) {
    int blk = blockIdx.x;
    int b = blk / NO, o1 = blk % NO;
    __shared__ float w1s[MT];
    __shared__ int s1v;
    if (threadIdx.x < MT) w1s[threadIdx.x] = wtab[o1 * MT + threadIdx.x];
    if (threadIdx.x == 0) s1v = wstart[o1];
    __syncthreads();
    const float* Sb = S + (size_t)b * NI * (NO * NO * NC);
    float* ob = out + (size_t)blk * (NO * NO * NC);
    int st = s1v;
    for (int e = threadIdx.x; e < NO * NO * NC; e += 256) {
        float a = 0.f;
        #pragma unroll
        for (int k = 0; k < MT; ++k) {
            int i1 = st + k; i1 = (i1 < NI) ? i1 : (NI - 1);
            a += w1s[k] * Sb[(size_t)i1 * (NO * NO * NC) + e];
        }
        ob[e] = a;
    }
}

// ---------------------------------------------------------------------------
extern "C" void kernel_launch(void* const* d_in, const int* in_sizes, int n_in,
                              void* d_out, int out_size, void* d_ws, size_t ws_size,
                              hipStream_t stream) {
    (void)in_sizes; (void)n_in; (void)out_size;
    const float* img  = (const float*)d_in[0];
    const float* kern = (const float*)d_in[1];
    float* out = (float*)d_out;
    char* ws = (char*)d_ws;

    const size_t TAB = 32768;
    if (ws_size >= TAB + A1_BYTES + A2_BYTES) {
        float* wa3 = (float*)ws;
        int*   j3  = (int*)(ws + 3456);
        float* w1  = (float*)(ws + 4096);
        int*   o1  = (int*)(ws + 8192);
        float* w0  = (float*)(ws + 12288);
        int*   o0  = (int*)(ws + 16384);
        float* A1  = (float*)(ws + TAB);
        float* A2  = (float*)(ws + TAB + A1_BYTES);

        k_setup3<<<3, 1024, 0, stream>>>(kern, wa3, j3, w1, o1, w0, o0);
        k_p1<<<NB * NI * (NI / 8), 256, 0, stream>>>(img, wa3, j3, A1);
        int p2b = (int)((P2_THREADS + 255) / 256);
        k_p2<<<p2b, 256, 0, stream>>>(A1, w1, o1, A2);
        int p3b = (int)((P3_THREADS + 255) / 256);
        k_p3<<<p3b, 256, 0, stream>>>(A2, w0, o0, out);
    } else {
        float* wtab   = (float*)ws;
        int*   wstart = (int*)(ws + 8256);
        float* S      = (float*)(ws + TAB);
        k_setup<<<1, 256, 0, stream>>>(kern, wtab, wstart);
        k_passA<<<NB * NI, 256, 0, stream>>>(img, wtab, wstart, S);
        k_passB<<<NB * NO, 256, 0, stream>>>(S, wtab, wstart, out);
    }
}